// Round 1
// baseline (453.874 us; speedup 1.0000x reference)
//
#include <hip/hip_runtime.h>
#include <hip/hip_bf16.h>
#include <cstddef>
#include <cstdint>

// Problem dims (fixed): B=512, T=64, D=128, H=128, FA=64
#define DEVI __device__ __forceinline__

DEVI float fast_rcp(float x) { return __builtin_amdgcn_rcpf(x); }
DEVI float sigmoid_fast(float x) { return fast_rcp(1.0f + __expf(-x)); }
DEVI float tanh_fast(float x) { return 1.0f - 2.0f * fast_rcp(__expf(2.0f * x) + 1.0f); }
DEVI float4 ld4(const float* p) { return *reinterpret_cast<const float4*>(p); }
DEVI void st4(float* p, float4 v) { *reinterpret_cast<float4*>(p) = v; }
DEVI float rlane(float v, int l) {
  int iv = __builtin_bit_cast(int, v);
  int r = __builtin_amdgcn_readlane(iv, l);
  return __builtin_bit_cast(float, r);
}
DEVI float f4c(const float4& v, int i) { return i == 0 ? v.x : i == 1 ? v.y : i == 2 ? v.z : v.w; }

// ---------------------------------------------------------------------------
// K1: attribute attention -> alpha_attri[128]. One block, 128 threads.
// ---------------------------------------------------------------------------
__global__ __launch_bounds__(128) void k_alpha(
    const float* __restrict__ AD, const float* __restrict__ W1,
    const float* __restrict__ B1, const float* __restrict__ W2,
    const float* __restrict__ B2, float* __restrict__ alpha) {
  __shared__ float sW1[64 * 32];
  __shared__ float sW2[32];
  __shared__ float sB1[32];
  __shared__ float red[128];
  __shared__ float s_mx, s_sum;
  int tid = threadIdx.x;
  for (int i = tid; i < 64 * 32; i += 128) sW1[i] = W1[i];
  if (tid < 32) { sW2[tid] = W2[tid]; sB1[tid] = B1[tid]; }
  __syncthreads();
  float ad[64];
  #pragma unroll
  for (int f = 0; f < 64; ++f) ad[f] = AD[tid * 64 + f];
  float logit = B2[0];
  #pragma unroll
  for (int j = 0; j < 32; ++j) {
    float a = sB1[j];
    #pragma unroll
    for (int f = 0; f < 64; ++f) a = fmaf(ad[f], sW1[f * 32 + j], a);
    a = a > 0.0f ? a : 0.5f * a;  // LeakyReLU(0.5)
    logit = fmaf(a, sW2[j], logit);
  }
  red[tid] = logit;
  __syncthreads();
  if (tid == 0) {
    float mx = red[0];
    for (int i = 1; i < 128; ++i) mx = fmaxf(mx, red[i]);
    float sm = 0.0f;
    for (int i = 0; i < 128; ++i) sm += __expf(red[i] - mx);
    s_mx = mx; s_sum = sm;
  }
  __syncthreads();
  alpha[tid] = __expf(logit - s_mx) / s_sum;
}

// ---------------------------------------------------------------------------
// K2: gxw[b,t,j] = sum_d X[b,t,d]*alpha[d]*w_ih[j,d] + b_ih[j] + b_hh[j]
// M=32768 rows(b*64+t), N=512, K=128. Block: 64 rows x 64 cols, 256 thr.
// ---------------------------------------------------------------------------
__global__ __launch_bounds__(256) void k_gxw(
    const float* __restrict__ X, const float* __restrict__ w_ih,
    const float* __restrict__ b_ih, const float* __restrict__ b_hh,
    const float* __restrict__ alpha, float* __restrict__ gxw) {
  __shared__ float Xs[64][132];
  __shared__ float Ws[64][132];
  int bid = blockIdx.x;
  int rt = bid >> 3, ct = bid & 7;
  int r0 = rt * 64, j0 = ct * 64;
  int tid = threadIdx.x;
  #pragma unroll
  for (int i = 0; i < 8; ++i) {
    int l4 = i * 256 + tid;           // 0..2047 float4s
    int r = l4 >> 5, d4 = l4 & 31;
    float4 xv = ld4(&X[(size_t)(r0 + r) * 128 + d4 * 4]);
    float4 av = ld4(&alpha[d4 * 4]);
    xv.x *= av.x; xv.y *= av.y; xv.z *= av.z; xv.w *= av.w;
    st4(&Xs[r][d4 * 4], xv);
    st4(&Ws[r][d4 * 4], ld4(&w_ih[(size_t)(j0 + r) * 128 + d4 * 4]));
  }
  __syncthreads();
  int cg = tid & 15, rg = tid >> 4;   // cols: cg + 16*jj ; rows: rg*4 + i
  int rr = rg * 4;
  float acc[4][4] = {};
  #pragma unroll
  for (int k4 = 0; k4 < 32; ++k4) {
    float4 xa[4], wa[4];
    #pragma unroll
    for (int i = 0; i < 4; ++i) xa[i] = ld4(&Xs[rr + i][k4 * 4]);
    #pragma unroll
    for (int j = 0; j < 4; ++j) wa[j] = ld4(&Ws[cg + 16 * j][k4 * 4]);
    #pragma unroll
    for (int i = 0; i < 4; ++i)
      #pragma unroll
      for (int j = 0; j < 4; ++j) {
        acc[i][j] = fmaf(xa[i].x, wa[j].x, acc[i][j]);
        acc[i][j] = fmaf(xa[i].y, wa[j].y, acc[i][j]);
        acc[i][j] = fmaf(xa[i].z, wa[j].z, acc[i][j]);
        acc[i][j] = fmaf(xa[i].w, wa[j].w, acc[i][j]);
      }
  }
  #pragma unroll
  for (int j = 0; j < 4; ++j) {
    int jj = j0 + cg + 16 * j;
    float bias = b_ih[jj] + b_hh[jj];
    #pragma unroll
    for (int i = 0; i < 4; ++i)
      gxw[(size_t)(r0 + rr + i) * 512 + jj] = acc[i][j] + bias;
  }
}

// ---------------------------------------------------------------------------
// K2c: EP[b,d,k] = exp(clamp(2*(alpha[d]*sum_tau X[b,tau,d]*w_a1[256+tau,k] + b_a1[k])))
// One block per b. 256 threads, outputs 128x128.
// ---------------------------------------------------------------------------
__global__ __launch_bounds__(256) void k_ep(
    const float* __restrict__ X, const float* __restrict__ w_a1,
    const float* __restrict__ b_a1, const float* __restrict__ alpha,
    float* __restrict__ EP) {
  __shared__ float Xb[64][128];
  __shared__ float Wx[64][128];
  int b = blockIdx.x;
  int tid = threadIdx.x;
  #pragma unroll
  for (int i = 0; i < 8; ++i) {
    int l4 = i * 256 + tid;
    int r = l4 >> 5, c4 = l4 & 31;
    st4(&Xb[r][c4 * 4], ld4(&X[((size_t)b * 64 + r) * 128 + c4 * 4]));
    st4(&Wx[r][c4 * 4], ld4(&w_a1[(size_t)(256 + r) * 128 + c4 * 4]));
  }
  __syncthreads();
  int dg = tid & 15, kg = tid >> 4;
  // rows d: {dg*4+i, 64+dg*4+i}, cols k: {kg*4+j, 64+kg*4+j}
  float acc[8][8] = {};
  #pragma unroll 4
  for (int tau = 0; tau < 64; ++tau) {
    float4 xa0 = ld4(&Xb[tau][dg * 4]);
    float4 xa1 = ld4(&Xb[tau][64 + dg * 4]);
    float4 wa0 = ld4(&Wx[tau][kg * 4]);
    float4 wa1 = ld4(&Wx[tau][64 + kg * 4]);
    #pragma unroll
    for (int i = 0; i < 8; ++i) {
      float xv = (i < 4) ? f4c(xa0, i) : f4c(xa1, i - 4);
      #pragma unroll
      for (int j = 0; j < 4; ++j) {
        acc[i][j]     = fmaf(xv, f4c(wa0, j), acc[i][j]);
        acc[i][j + 4] = fmaf(xv, f4c(wa1, j), acc[i][j + 4]);
      }
    }
  }
  float4 ba0 = ld4(&b_a1[kg * 4]);
  float4 ba1v = ld4(&b_a1[64 + kg * 4]);
  #pragma unroll
  for (int i = 0; i < 8; ++i) {
    int drow = (i < 4) ? dg * 4 + i : 64 + dg * 4 + (i - 4);
    float al = alpha[drow];
    float4 o0, o1;
    float* p0 = &o0.x; float* p1 = &o1.x;
    #pragma unroll
    for (int j = 0; j < 4; ++j) {
      float v0 = 2.0f * fmaf(al, acc[i][j],     f4c(ba0, j));
      float v1 = 2.0f * fmaf(al, acc[i][j + 4], f4c(ba1v, j));
      p0[j] = __expf(fminf(fmaxf(v0, -40.0f), 40.0f));
      p1[j] = __expf(fminf(fmaxf(v1, -40.0f), 40.0f));
    }
    st4(&EP[((size_t)b * 128 + drow) * 128 + kg * 4], o0);
    st4(&EP[((size_t)b * 128 + drow) * 128 + 64 + kg * 4], o1);
  }
}

// ---------------------------------------------------------------------------
// K3: LSTM recurrence. 256 blocks x 512 threads, 2 batch elems per block.
// Stores pre-update states S[t][b][0:128]=h, [128:256]=c.
// ---------------------------------------------------------------------------
__global__ __launch_bounds__(512, 2) void k_lstm(
    const float* __restrict__ gxw, const float* __restrict__ w_hh,
    float* __restrict__ S) {
  __shared__ float h_lds[2][128];
  __shared__ float c_lds[2][128];
  __shared__ float g_lds[2][512];
  int tid = threadIdx.x;
  int b0 = blockIdx.x * 2;
  float4 w4[32];
  #pragma unroll
  for (int q = 0; q < 32; ++q)
    w4[q] = ld4(&w_hh[(size_t)tid * 128 + q * 4]);
  if (tid < 256) {
    h_lds[tid >> 7][tid & 127] = 0.0f;
    c_lds[tid >> 7][tid & 127] = 0.0f;
  }
  __syncthreads();
  int lane = tid & 63;
  for (int t = 0; t < 64; ++t) {
    // write pre-update states
    {
      int b = tid >> 8, idx = tid & 255;
      float v = (idx < 128) ? h_lds[b][idx] : c_lds[b][idx - 128];
      S[((size_t)t * 512 + b0 + b) * 256 + idx] = v;
    }
    // gates: thread owns gate-row `tid` for both b
    #pragma unroll
    for (int bb = 0; bb < 2; ++bb) {
      float gx = gxw[((size_t)(b0 + bb) * 64 + t) * 512 + tid];
      float h0 = h_lds[bb][lane];
      float h1 = h_lds[bb][64 + lane];
      float a0 = 0.f, a1 = 0.f, a2 = 0.f, a3 = 0.f;
      #pragma unroll
      for (int q = 0; q < 16; ++q) {
        a0 = fmaf(rlane(h0, 4 * q + 0), w4[q].x, a0);
        a1 = fmaf(rlane(h0, 4 * q + 1), w4[q].y, a1);
        a2 = fmaf(rlane(h0, 4 * q + 2), w4[q].z, a2);
        a3 = fmaf(rlane(h0, 4 * q + 3), w4[q].w, a3);
      }
      #pragma unroll
      for (int q = 0; q < 16; ++q) {
        a0 = fmaf(rlane(h1, 4 * q + 0), w4[16 + q].x, a0);
        a1 = fmaf(rlane(h1, 4 * q + 1), w4[16 + q].y, a1);
        a2 = fmaf(rlane(h1, 4 * q + 2), w4[16 + q].z, a2);
        a3 = fmaf(rlane(h1, 4 * q + 3), w4[16 + q].w, a3);
      }
      g_lds[bb][tid] = gx + ((a0 + a1) + (a2 + a3));
    }
    __syncthreads();
    if (tid < 256) {
      int b = tid >> 7, m = tid & 127;
      float ig = sigmoid_fast(g_lds[b][m]);
      float fg = sigmoid_fast(g_lds[b][128 + m]);
      float gg = tanh_fast(g_lds[b][256 + m]);
      float og = sigmoid_fast(g_lds[b][384 + m]);
      float cn = fmaf(fg, c_lds[b][m], ig * gg);
      float hn = og * tanh_fast(cn);
      c_lds[b][m] = cn;
      h_lds[b][m] = hn;
    }
    __syncthreads();
  }
}

// ---------------------------------------------------------------------------
// K4: EQ[t,b,k] = exp(clamp(2 * sum_{m<256} S[t,b,m]*w_a1[m,k]))
// rows 32768 (t*512+b), K=256, N=128. Block: 64 rows x 128 cols, 256 thr.
// ---------------------------------------------------------------------------
__global__ __launch_bounds__(256) void k_eq(
    const float* __restrict__ S, const float* __restrict__ w_a1,
    float* __restrict__ EQ) {
  __shared__ float Ss[64][68];
  __shared__ float Wc[64][128];
  int r0 = blockIdx.x * 64;
  int tid = threadIdx.x;
  int kg = tid & 15, rg = tid >> 4;
  int rr = rg * 4;
  float acc[4][8] = {};
  for (int kc = 0; kc < 4; ++kc) {
    if (kc) __syncthreads();
    #pragma unroll
    for (int i = 0; i < 4; ++i) {
      int l4 = i * 256 + tid;          // 1024 float4 = 64 x 16
      int r = l4 >> 4, c4 = l4 & 15;
      st4(&Ss[r][c4 * 4], ld4(&S[(size_t)(r0 + r) * 256 + kc * 64 + c4 * 4]));
    }
    #pragma unroll
    for (int i = 0; i < 8; ++i) {
      int l4 = i * 256 + tid;          // 2048 float4 = 64 x 32
      int r = l4 >> 5, c4 = l4 & 31;
      st4(&Wc[r][c4 * 4], ld4(&w_a1[(size_t)(kc * 64 + r) * 128 + c4 * 4]));
    }
    __syncthreads();
    #pragma unroll 2
    for (int k = 0; k < 64; k += 4) {
      float4 sa[4];
      #pragma unroll
      for (int i = 0; i < 4; ++i) sa[i] = ld4(&Ss[rr + i][k]);
      #pragma unroll
      for (int kk = 0; kk < 4; ++kk) {
        float4 wa0 = ld4(&Wc[k + kk][kg * 4]);
        float4 wa1 = ld4(&Wc[k + kk][64 + kg * 4]);
        #pragma unroll
        for (int i = 0; i < 4; ++i) {
          float sv = f4c(sa[i], kk);
          #pragma unroll
          for (int j = 0; j < 4; ++j) {
            acc[i][j]     = fmaf(sv, f4c(wa0, j), acc[i][j]);
            acc[i][j + 4] = fmaf(sv, f4c(wa1, j), acc[i][j + 4]);
          }
        }
      }
    }
  }
  #pragma unroll
  for (int i = 0; i < 4; ++i) {
    float4 o0, o1;
    float* p0 = &o0.x; float* p1 = &o1.x;
    #pragma unroll
    for (int j = 0; j < 4; ++j) {
      float v0 = 2.0f * acc[i][j];
      float v1 = 2.0f * acc[i][j + 4];
      p0[j] = __expf(fminf(fmaxf(v0, -40.0f), 40.0f));
      p1[j] = __expf(fminf(fmaxf(v1, -40.0f), 40.0f));
    }
    st4(&EQ[(size_t)(r0 + rr + i) * 128 + kg * 4], o0);
    st4(&EQ[(size_t)(r0 + rr + i) * 128 + 64 + kg * 4], o1);
  }
}

// ---------------------------------------------------------------------------
// K5: per (b): for each t: e'[d] = -2*sum_k w_a2[k]*rcp(EP[b,d,k]*EQ[t,b,k]+1);
// softmax over d; out[b,t,d] = sm * alpha[d] * X[b,t,d].
// 512 blocks (b) x 512 threads. EP in registers, EQ in LDS.
// ---------------------------------------------------------------------------
__global__ __launch_bounds__(512, 4) void k_attn(
    const float* __restrict__ EP, const float* __restrict__ EQ,
    const float* __restrict__ w_a2, const float* __restrict__ alpha,
    const float* __restrict__ X, float* __restrict__ out) {
  __shared__ float EQs[64][128];
  __shared__ float e_lds[128];
  int b = blockIdx.x;
  int tid = threadIdx.x;
  #pragma unroll
  for (int i = 0; i < 4; ++i) {
    int l4 = i * 512 + tid;            // 2048 float4 = 64 x 32
    int t = l4 >> 5, k4 = l4 & 31;
    st4(&EQs[t][k4 * 4], ld4(&EQ[((size_t)t * 512 + b) * 128 + k4 * 4]));
  }
  int d = tid >> 2, s = tid & 3;
  float4 ep[8], w2r[8];
  #pragma unroll
  for (int q = 0; q < 8; ++q) {
    ep[q]  = ld4(&EP[((size_t)b * 128 + d) * 128 + s * 32 + q * 4]);
    w2r[q] = ld4(&w_a2[s * 32 + q * 4]);
  }
  __syncthreads();
  for (int t = 0; t < 64; ++t) {
    float p = 0.0f;
    #pragma unroll
    for (int q = 0; q < 8; ++q) {
      float4 eq = ld4(&EQs[t][s * 32 + q * 4]);
      p = fmaf(w2r[q].x, fast_rcp(fmaf(ep[q].x, eq.x, 1.0f)), p);
      p = fmaf(w2r[q].y, fast_rcp(fmaf(ep[q].y, eq.y, 1.0f)), p);
      p = fmaf(w2r[q].z, fast_rcp(fmaf(ep[q].z, eq.z, 1.0f)), p);
      p = fmaf(w2r[q].w, fast_rcp(fmaf(ep[q].w, eq.w, 1.0f)), p);
    }
    p += __shfl_xor(p, 1);
    p += __shfl_xor(p, 2);
    if (s == 0) e_lds[d] = -2.0f * p;
    __syncthreads();
    if (tid < 128) {
      int lane = tid & 63;
      float v0 = e_lds[lane], v1 = e_lds[64 + lane];
      float mx = fmaxf(v0, v1);
      #pragma unroll
      for (int o = 1; o < 64; o <<= 1) mx = fmaxf(mx, __shfl_xor(mx, o));
      float e0 = __expf(v0 - mx), e1 = __expf(v1 - mx);
      float sm = e0 + e1;
      #pragma unroll
      for (int o = 1; o < 64; o <<= 1) sm += __shfl_xor(sm, o);
      float inv = fast_rcp(sm);
      float ev = (tid < 64) ? e0 : e1;
      float av = ev * inv * alpha[tid];
      out[((size_t)b * 64 + t) * 128 + tid] = av * X[((size_t)b * 64 + t) * 128 + tid];
    }
    __syncthreads();
  }
}

// ---------------------------------------------------------------------------
extern "C" void kernel_launch(void* const* d_in, const int* in_sizes, int n_in,
                              void* d_out, int out_size, void* d_ws, size_t ws_size,
                              hipStream_t stream) {
  const float* X    = (const float*)d_in[0];
  const float* AD   = (const float*)d_in[1];
  const float* W1   = (const float*)d_in[2];
  const float* B1   = (const float*)d_in[3];
  const float* W2   = (const float*)d_in[4];
  const float* B2   = (const float*)d_in[5];
  const float* w_a1 = (const float*)d_in[6];
  const float* b_a1 = (const float*)d_in[7];
  const float* w_a2 = (const float*)d_in[8];
  // d_in[9] = b_a2: softmax-invariant, unused
  const float* w_ih = (const float*)d_in[10];
  const float* w_hh = (const float*)d_in[11];
  const float* b_ih = (const float*)d_in[12];
  const float* b_hh = (const float*)d_in[13];
  float* out = (float*)d_out;
  float* ws = (float*)d_ws;

  // workspace layout (floats). EQ aliases gxw (gxw dead after k_lstm).
  float* alpha = ws;                       // 128 (pad to 256)
  float* gxw   = ws + 256;                 // 32768*512 = 16777216
  float* EQ    = gxw;                      // 32768*128 = 4194304 (alias, after k_lstm)
  float* EP    = gxw + 16777216;           // 65536*128 = 8388608
  float* S     = EP + 8388608;             // 32768*256 = 8388608
  // total: 256 + 16777216 + 8388608 + 8388608 = 33554688 floats ~= 128 MB

  hipLaunchKernelGGL(k_alpha, dim3(1), dim3(128), 0, stream, AD, W1, B1, W2, B2, alpha);
  hipLaunchKernelGGL(k_gxw,  dim3(4096), dim3(256), 0, stream, X, w_ih, b_ih, b_hh, alpha, gxw);
  hipLaunchKernelGGL(k_ep,   dim3(512),  dim3(256), 0, stream, X, w_a1, b_a1, alpha, EP);
  hipLaunchKernelGGL(k_lstm, dim3(256),  dim3(512), 0, stream, gxw, w_hh, S);
  hipLaunchKernelGGL(k_eq,   dim3(512),  dim3(256), 0, stream, S, w_a1, EQ);
  hipLaunchKernelGGL(k_attn, dim3(512),  dim3(512), 0, stream, EP, EQ, w_a2, alpha, X, out);
}

// Round 2
// 356.171 us; speedup vs baseline: 1.2743x; 1.2743x over previous
//
#include <hip/hip_runtime.h>
#include <hip/hip_bf16.h>
#include <cstddef>
#include <cstdint>

// Problem dims (fixed): B=512, T=64, D=128, H=128, FA=64
#define DEVI __device__ __forceinline__

typedef float f32x4 __attribute__((ext_vector_type(4)));
typedef __bf16 bf16x8 __attribute__((ext_vector_type(8)));

DEVI float fast_rcp(float x) { return __builtin_amdgcn_rcpf(x); }
DEVI float sigmoid_fast(float x) { return fast_rcp(1.0f + __expf(-x)); }
DEVI float tanh_fast(float x) { return 1.0f - 2.0f * fast_rcp(__expf(2.0f * x) + 1.0f); }
DEVI float4 ld4(const float* p) { return *reinterpret_cast<const float4*>(p); }
DEVI void st4(float* p, float4 v) { *reinterpret_cast<float4*>(p) = v; }
DEVI float f4c(const float4& v, int i) { return i == 0 ? v.x : i == 1 ? v.y : i == 2 ? v.z : v.w; }
DEVI unsigned short bfbits(float f) { return __builtin_bit_cast(unsigned short, (__bf16)f); }
DEVI unsigned pack2(float a, float b) {
  return (unsigned)bfbits(a) | ((unsigned)bfbits(b) << 16);
}

// ---------------------------------------------------------------------------
// K1: attribute attention -> alpha_attri[128]. One block, 128 threads.
// ---------------------------------------------------------------------------
__global__ __launch_bounds__(128) void k_alpha(
    const float* __restrict__ AD, const float* __restrict__ W1,
    const float* __restrict__ B1, const float* __restrict__ W2,
    const float* __restrict__ B2, float* __restrict__ alpha) {
  __shared__ float sW1[64 * 32];
  __shared__ float sW2[32];
  __shared__ float sB1[32];
  __shared__ float red[128];
  __shared__ float s_mx, s_sum;
  int tid = threadIdx.x;
  for (int i = tid; i < 64 * 32; i += 128) sW1[i] = W1[i];
  if (tid < 32) { sW2[tid] = W2[tid]; sB1[tid] = B1[tid]; }
  __syncthreads();
  float ad[64];
  #pragma unroll
  for (int f = 0; f < 64; ++f) ad[f] = AD[tid * 64 + f];
  float logit = B2[0];
  #pragma unroll
  for (int j = 0; j < 32; ++j) {
    float a = sB1[j];
    #pragma unroll
    for (int f = 0; f < 64; ++f) a = fmaf(ad[f], sW1[f * 32 + j], a);
    a = a > 0.0f ? a : 0.5f * a;  // LeakyReLU(0.5)
    logit = fmaf(a, sW2[j], logit);
  }
  red[tid] = logit;
  __syncthreads();
  if (tid == 0) {
    float mx = red[0];
    for (int i = 1; i < 128; ++i) mx = fmaxf(mx, red[i]);
    float sm = 0.0f;
    for (int i = 0; i < 128; ++i) sm += __expf(red[i] - mx);
    s_mx = mx; s_sum = sm;
  }
  __syncthreads();
  alpha[tid] = __expf(logit - s_mx) / s_sum;
}

// ---------------------------------------------------------------------------
// K2: EP[b,d,k] = exp(clamp(2*(alpha[d]*sum_tau X[b,tau,d]*w_a1[256+tau,k] + b_a1[k])))
// One block per b. 256 threads, outputs 128x128.
// ---------------------------------------------------------------------------
__global__ __launch_bounds__(256) void k_ep(
    const float* __restrict__ X, const float* __restrict__ w_a1,
    const float* __restrict__ b_a1, const float* __restrict__ alpha,
    float* __restrict__ EP) {
  __shared__ float Xb[64][128];
  __shared__ float Wx[64][128];
  int b = blockIdx.x;
  int tid = threadIdx.x;
  #pragma unroll
  for (int i = 0; i < 8; ++i) {
    int l4 = i * 256 + tid;
    int r = l4 >> 5, c4 = l4 & 31;
    st4(&Xb[r][c4 * 4], ld4(&X[((size_t)b * 64 + r) * 128 + c4 * 4]));
    st4(&Wx[r][c4 * 4], ld4(&w_a1[(size_t)(256 + r) * 128 + c4 * 4]));
  }
  __syncthreads();
  int dg = tid & 15, kg = tid >> 4;
  float acc[8][8] = {};
  #pragma unroll 4
  for (int tau = 0; tau < 64; ++tau) {
    float4 xa0 = ld4(&Xb[tau][dg * 4]);
    float4 xa1 = ld4(&Xb[tau][64 + dg * 4]);
    float4 wa0 = ld4(&Wx[tau][kg * 4]);
    float4 wa1 = ld4(&Wx[tau][64 + kg * 4]);
    #pragma unroll
    for (int i = 0; i < 8; ++i) {
      float xv = (i < 4) ? f4c(xa0, i) : f4c(xa1, i - 4);
      #pragma unroll
      for (int j = 0; j < 4; ++j) {
        acc[i][j]     = fmaf(xv, f4c(wa0, j), acc[i][j]);
        acc[i][j + 4] = fmaf(xv, f4c(wa1, j), acc[i][j + 4]);
      }
    }
  }
  float4 ba0 = ld4(&b_a1[kg * 4]);
  float4 ba1v = ld4(&b_a1[64 + kg * 4]);
  #pragma unroll
  for (int i = 0; i < 8; ++i) {
    int drow = (i < 4) ? dg * 4 + i : 64 + dg * 4 + (i - 4);
    float al = alpha[drow];
    float4 o0, o1;
    float* p0 = &o0.x; float* p1 = &o1.x;
    #pragma unroll
    for (int j = 0; j < 4; ++j) {
      float v0 = 2.0f * fmaf(al, acc[i][j],     f4c(ba0, j));
      float v1 = 2.0f * fmaf(al, acc[i][j + 4], f4c(ba1v, j));
      p0[j] = __expf(fminf(fmaxf(v0, -40.0f), 40.0f));
      p1[j] = __expf(fminf(fmaxf(v1, -40.0f), 40.0f));
    }
    st4(&EP[((size_t)b * 128 + drow) * 128 + kg * 4], o0);
    st4(&EP[((size_t)b * 128 + drow) * 128 + 64 + kg * 4], o1);
  }
}

// ---------------------------------------------------------------------------
// K3: fused gxw + LSTM recurrence via bf16 MFMA.
// 32 blocks x 512 threads; block owns 16 batches. Per step t:
//   gates[512j x 16b] = [w_ih*alpha | w_hh]([512,256] bf16 A-frags in VGPRs)
//                       @ [x_t ; h]([256,16] bf16 B-frags from swizzled LDS)
// Cell update in C-frag registers; writes pre-update (h,c) to S.
// C/D layout (HW-verified): col=lane&15 (batch), row=(lane>>4)*4+reg (j local).
// A/B use the same (lane-group,elem)->k packing, so the result is invariant
// to the exact HW k-permutation.
// ---------------------------------------------------------------------------
__global__ __launch_bounds__(512, 2) void k_rec(
    const float* __restrict__ X, const float* __restrict__ w_ih,
    const float* __restrict__ w_hh, const float* __restrict__ b_ih,
    const float* __restrict__ b_hh, const float* __restrict__ alpha,
    float* __restrict__ S) {
  // kB[b][k], k in [0,256): 0..127 = x_t(d), 128..255 = h(m). bf16.
  // 16-byte granule XOR swizzle: granule g of row b stored at g^(b&7).
  __shared__ unsigned short kB[16 * 256];
  int tid = threadIdx.x;
  int wv = tid >> 6, l = tid & 63, lg = l >> 4, lr = l & 15;
  int b0 = blockIdx.x * 16;

  // ---- A fragments: afr[ks][quad], ks 0..3 = w_ih*alpha, 4..7 = w_hh ----
  bf16x8 afr[8][4];
  #pragma unroll
  for (int ks = 0; ks < 8; ++ks) {
    int kb = (ks & 3) * 32 + lg * 8;
    float4 a0, a1;
    if (ks < 4) { a0 = ld4(&alpha[kb]); a1 = ld4(&alpha[kb + 4]); }
    #pragma unroll
    for (int q = 0; q < 4; ++q) {
      int j = q * 128 + wv * 16 + lr;
      const float* src = (ks < 4) ? &w_ih[(size_t)j * 128 + kb]
                                  : &w_hh[(size_t)j * 128 + kb];
      float4 f0 = ld4(src), f1 = ld4(src + 4);
      if (ks < 4) {
        f0.x *= a0.x; f0.y *= a0.y; f0.z *= a0.z; f0.w *= a0.w;
        f1.x *= a1.x; f1.y *= a1.y; f1.z *= a1.z; f1.w *= a1.w;
      }
      bf16x8 fr;
      fr[0] = (__bf16)f0.x; fr[1] = (__bf16)f0.y;
      fr[2] = (__bf16)f0.z; fr[3] = (__bf16)f0.w;
      fr[4] = (__bf16)f1.x; fr[5] = (__bf16)f1.y;
      fr[6] = (__bf16)f1.z; fr[7] = (__bf16)f1.w;
      afr[ks][q] = fr;
    }
  }

  // ---- biases per C-slot: j = q*128 + wv*16 + lg*4 + r ----
  float bias[4][4];
  #pragma unroll
  for (int q = 0; q < 4; ++q)
    #pragma unroll
    for (int r = 0; r < 4; ++r) {
      int j = q * 128 + wv * 16 + lg * 4 + r;
      bias[q][r] = b_ih[j] + b_hh[j];
    }

  alignas(16) float hA[4] = {0.f, 0.f, 0.f, 0.f};
  alignas(16) float cA[4] = {0.f, 0.f, 0.f, 0.f};

  int bi = tid >> 5, d4 = tid & 31, d0 = d4 * 4;       // x-staging role
  int m0 = wv * 16 + lg * 4;                           // this lane's h rows
  int k0 = 128 + m0;
  unsigned short* xdst = &kB[bi * 256 + (((d0 >> 3) ^ (bi & 7)) << 3) + (d0 & 7)];
  unsigned short* hdst = &kB[lr * 256 + ((((k0 >> 3) ^ (lr & 7))) << 3) + (k0 & 7)];

  for (int t = 0; t < 64; ++t) {
    // ---- stage: S (pre-update states), x_t, h into LDS ----
    size_t srow = ((size_t)(t * 512) + b0 + lr) * 256;
    st4(&S[srow + m0], *reinterpret_cast<const float4*>(hA));
    st4(&S[srow + 128 + m0], *reinterpret_cast<const float4*>(cA));

    float4 xv = ld4(&X[(((size_t)(b0 + bi)) * 64 + t) * 128 + d0]);
    uint2 xu; xu.x = pack2(xv.x, xv.y); xu.y = pack2(xv.z, xv.w);
    *reinterpret_cast<uint2*>(xdst) = xu;

    uint2 hu; hu.x = pack2(hA[0], hA[1]); hu.y = pack2(hA[2], hA[3]);
    *reinterpret_cast<uint2*>(hdst) = hu;

    __syncthreads();

    // ---- B fragments (shared across quads) ----
    bf16x8 bfr[8];
    #pragma unroll
    for (int ks = 0; ks < 8; ++ks) {
      int kb = ks * 32 + lg * 8;
      int idx = lr * 256 + (((kb >> 3) ^ (lr & 7)) << 3) + (kb & 7);
      bfr[ks] = *reinterpret_cast<const bf16x8*>(&kB[idx]);
    }

    // ---- 32 MFMA: gates quadrants i,f,g,o ----
    f32x4 acc0 = {0.f, 0.f, 0.f, 0.f}, acc1 = acc0, acc2 = acc0, acc3 = acc0;
    #pragma unroll
    for (int ks = 0; ks < 8; ++ks) {
      acc0 = __builtin_amdgcn_mfma_f32_16x16x32_bf16(afr[ks][0], bfr[ks], acc0, 0, 0, 0);
      acc1 = __builtin_amdgcn_mfma_f32_16x16x32_bf16(afr[ks][1], bfr[ks], acc1, 0, 0, 0);
      acc2 = __builtin_amdgcn_mfma_f32_16x16x32_bf16(afr[ks][2], bfr[ks], acc2, 0, 0, 0);
      acc3 = __builtin_amdgcn_mfma_f32_16x16x32_bf16(afr[ks][3], bfr[ks], acc3, 0, 0, 0);
    }

    // ---- cell update (per lane: 4 (batch,m) slots) ----
    #pragma unroll
    for (int r = 0; r < 4; ++r) {
      float ig = sigmoid_fast(acc0[r] + bias[0][r]);
      float fg = sigmoid_fast(acc1[r] + bias[1][r]);
      float gg = tanh_fast(acc2[r] + bias[2][r]);
      float og = sigmoid_fast(acc3[r] + bias[3][r]);
      float cn = fmaf(fg, cA[r], ig * gg);
      float hn = og * tanh_fast(cn);
      cA[r] = cn;
      hA[r] = hn;
    }
    __syncthreads();
  }
}

// ---------------------------------------------------------------------------
// K4: EQ[t,b,k] = exp(clamp(2 * sum_{m<256} S[t,b,m]*w_a1[m,k]))
// rows 32768 (t*512+b), K=256, N=128. Block: 64 rows x 128 cols, 256 thr.
// ---------------------------------------------------------------------------
__global__ __launch_bounds__(256) void k_eq(
    const float* __restrict__ S, const float* __restrict__ w_a1,
    float* __restrict__ EQ) {
  __shared__ float Ss[64][68];
  __shared__ float Wc[64][128];
  int r0 = blockIdx.x * 64;
  int tid = threadIdx.x;
  int kg = tid & 15, rg = tid >> 4;
  int rr = rg * 4;
  float acc[4][8] = {};
  for (int kc = 0; kc < 4; ++kc) {
    if (kc) __syncthreads();
    #pragma unroll
    for (int i = 0; i < 4; ++i) {
      int l4 = i * 256 + tid;
      int r = l4 >> 4, c4 = l4 & 15;
      st4(&Ss[r][c4 * 4], ld4(&S[(size_t)(r0 + r) * 256 + kc * 64 + c4 * 4]));
    }
    #pragma unroll
    for (int i = 0; i < 8; ++i) {
      int l4 = i * 256 + tid;
      int r = l4 >> 5, c4 = l4 & 31;
      st4(&Wc[r][c4 * 4], ld4(&w_a1[(size_t)(kc * 64 + r) * 128 + c4 * 4]));
    }
    __syncthreads();
    #pragma unroll 2
    for (int k = 0; k < 64; k += 4) {
      float4 sa[4];
      #pragma unroll
      for (int i = 0; i < 4; ++i) sa[i] = ld4(&Ss[rr + i][k]);
      #pragma unroll
      for (int kk = 0; kk < 4; ++kk) {
        float4 wa0 = ld4(&Wc[k + kk][kg * 4]);
        float4 wa1 = ld4(&Wc[k + kk][64 + kg * 4]);
        #pragma unroll
        for (int i = 0; i < 4; ++i) {
          float sv = f4c(sa[i], kk);
          #pragma unroll
          for (int j = 0; j < 4; ++j) {
            acc[i][j]     = fmaf(sv, f4c(wa0, j), acc[i][j]);
            acc[i][j + 4] = fmaf(sv, f4c(wa1, j), acc[i][j + 4]);
          }
        }
      }
    }
  }
  #pragma unroll
  for (int i = 0; i < 4; ++i) {
    float4 o0, o1;
    float* p0 = &o0.x; float* p1 = &o1.x;
    #pragma unroll
    for (int j = 0; j < 4; ++j) {
      float v0 = 2.0f * acc[i][j];
      float v1 = 2.0f * acc[i][j + 4];
      p0[j] = __expf(fminf(fmaxf(v0, -40.0f), 40.0f));
      p1[j] = __expf(fminf(fmaxf(v1, -40.0f), 40.0f));
    }
    st4(&EQ[(size_t)(r0 + rr + i) * 128 + kg * 4], o0);
    st4(&EQ[(size_t)(r0 + rr + i) * 128 + 64 + kg * 4], o1);
  }
}

// ---------------------------------------------------------------------------
// K5: per (b): for each t: e'[d] = -2*sum_k w_a2[k]*rcp(EP[b,d,k]*EQ[t,b,k]+1);
// softmax over d; out[b,t,d] = sm * alpha[d] * X[b,t,d].
// ---------------------------------------------------------------------------
__global__ __launch_bounds__(512, 4) void k_attn(
    const float* __restrict__ EP, const float* __restrict__ EQ,
    const float* __restrict__ w_a2, const float* __restrict__ alpha,
    const float* __restrict__ X, float* __restrict__ out) {
  __shared__ float EQs[64][128];
  __shared__ float e_lds[128];
  int b = blockIdx.x;
  int tid = threadIdx.x;
  #pragma unroll
  for (int i = 0; i < 4; ++i) {
    int l4 = i * 512 + tid;
    int t = l4 >> 5, k4 = l4 & 31;
    st4(&EQs[t][k4 * 4], ld4(&EQ[((size_t)t * 512 + b) * 128 + k4 * 4]));
  }
  int d = tid >> 2, s = tid & 3;
  float4 ep[8], w2r[8];
  #pragma unroll
  for (int q = 0; q < 8; ++q) {
    ep[q]  = ld4(&EP[((size_t)b * 128 + d) * 128 + s * 32 + q * 4]);
    w2r[q] = ld4(&w_a2[s * 32 + q * 4]);
  }
  __syncthreads();
  for (int t = 0; t < 64; ++t) {
    float p = 0.0f;
    #pragma unroll
    for (int q = 0; q < 8; ++q) {
      float4 eq = ld4(&EQs[t][s * 32 + q * 4]);
      p = fmaf(w2r[q].x, fast_rcp(fmaf(ep[q].x, eq.x, 1.0f)), p);
      p = fmaf(w2r[q].y, fast_rcp(fmaf(ep[q].y, eq.y, 1.0f)), p);
      p = fmaf(w2r[q].z, fast_rcp(fmaf(ep[q].z, eq.z, 1.0f)), p);
      p = fmaf(w2r[q].w, fast_rcp(fmaf(ep[q].w, eq.w, 1.0f)), p);
    }
    p += __shfl_xor(p, 1);
    p += __shfl_xor(p, 2);
    if (s == 0) e_lds[d] = -2.0f * p;
    __syncthreads();
    if (tid < 128) {
      int lane = tid & 63;
      float v0 = e_lds[lane], v1 = e_lds[64 + lane];
      float mx = fmaxf(v0, v1);
      #pragma unroll
      for (int o = 1; o < 64; o <<= 1) mx = fmaxf(mx, __shfl_xor(mx, o));
      float e0 = __expf(v0 - mx), e1 = __expf(v1 - mx);
      float sm = e0 + e1;
      #pragma unroll
      for (int o = 1; o < 64; o <<= 1) sm += __shfl_xor(sm, o);
      float inv = fast_rcp(sm);
      float ev = (tid < 64) ? e0 : e1;
      float av = ev * inv * alpha[tid];
      out[((size_t)b * 64 + t) * 128 + tid] = av * X[((size_t)b * 64 + t) * 128 + tid];
    }
    __syncthreads();
  }
}

// ---------------------------------------------------------------------------
extern "C" void kernel_launch(void* const* d_in, const int* in_sizes, int n_in,
                              void* d_out, int out_size, void* d_ws, size_t ws_size,
                              hipStream_t stream) {
  const float* X    = (const float*)d_in[0];
  const float* AD   = (const float*)d_in[1];
  const float* W1   = (const float*)d_in[2];
  const float* B1   = (const float*)d_in[3];
  const float* W2   = (const float*)d_in[4];
  const float* B2   = (const float*)d_in[5];
  const float* w_a1 = (const float*)d_in[6];
  const float* b_a1 = (const float*)d_in[7];
  const float* w_a2 = (const float*)d_in[8];
  // d_in[9] = b_a2: softmax-invariant, unused
  const float* w_ih = (const float*)d_in[10];
  const float* w_hh = (const float*)d_in[11];
  const float* b_ih = (const float*)d_in[12];
  const float* b_hh = (const float*)d_in[13];
  float* out = (float*)d_out;
  float* ws = (float*)d_ws;

  // workspace layout (floats)
  float* alpha = ws;                       // 128 (pad to 256)
  float* EQ    = ws + 256;                 // 32768*128 = 4194304
  float* EP    = EQ + 4194304;             // 65536*128 = 8388608
  float* S     = EP + 8388608;             // 32768*256 = 8388608
  // total ~= 21.0M floats ~= 84 MB

  hipLaunchKernelGGL(k_alpha, dim3(1), dim3(128), 0, stream, AD, W1, B1, W2, B2, alpha);
  hipLaunchKernelGGL(k_ep,   dim3(512), dim3(256), 0, stream, X, w_a1, b_a1, alpha, EP);
  hipLaunchKernelGGL(k_rec,  dim3(32),  dim3(512), 0, stream, X, w_ih, w_hh, b_ih, b_hh, alpha, S);
  hipLaunchKernelGGL(k_eq,   dim3(512), dim3(256), 0, stream, S, w_a1, EQ);
  hipLaunchKernelGGL(k_attn, dim3(512), dim3(512), 0, stream, EP, EQ, w_a2, alpha, X, out);
}

// Round 4
// 305.933 us; speedup vs baseline: 1.4836x; 1.1642x over previous
//
#include <hip/hip_runtime.h>
#include <hip/hip_bf16.h>
#include <cstddef>
#include <cstdint>

// Problem dims (fixed): B=512, T=64, D=128, H=128, FA=64
#define DEVI __device__ __forceinline__

typedef float f32x4 __attribute__((ext_vector_type(4)));
typedef __bf16 bf16x8 __attribute__((ext_vector_type(8)));

DEVI float fast_rcp(float x) { return __builtin_amdgcn_rcpf(x); }
DEVI float sigmoid_fast(float x) { return fast_rcp(1.0f + __expf(-x)); }
DEVI float tanh_fast(float x) { return 1.0f - 2.0f * fast_rcp(__expf(2.0f * x) + 1.0f); }
DEVI float4 ld4(const float* p) { return *reinterpret_cast<const float4*>(p); }
DEVI void st4(float* p, float4 v) { *reinterpret_cast<float4*>(p) = v; }
DEVI float f4c(const float4& v, int i) { return i == 0 ? v.x : i == 1 ? v.y : i == 2 ? v.z : v.w; }
DEVI unsigned short bfbits(float f) { return __builtin_bit_cast(unsigned short, (__bf16)f); }
DEVI unsigned pack2(float a, float b) {
  return (unsigned)bfbits(a) | ((unsigned)bfbits(b) << 16);
}

// ---------------------------------------------------------------------------
// K1: attribute attention -> alpha_attri[128]. One block, 128 threads.
// ---------------------------------------------------------------------------
__global__ __launch_bounds__(128) void k_alpha(
    const float* __restrict__ AD, const float* __restrict__ W1,
    const float* __restrict__ B1, const float* __restrict__ W2,
    const float* __restrict__ B2, float* __restrict__ alpha) {
  __shared__ float sW1[64 * 32];
  __shared__ float sW2[32];
  __shared__ float sB1[32];
  __shared__ float red[128];
  __shared__ float s_mx, s_sum;
  int tid = threadIdx.x;
  for (int i = tid; i < 64 * 32; i += 128) sW1[i] = W1[i];
  if (tid < 32) { sW2[tid] = W2[tid]; sB1[tid] = B1[tid]; }
  __syncthreads();
  float ad[64];
  #pragma unroll
  for (int f = 0; f < 64; ++f) ad[f] = AD[tid * 64 + f];
  float logit = B2[0];
  #pragma unroll
  for (int j = 0; j < 32; ++j) {
    float a = sB1[j];
    #pragma unroll
    for (int f = 0; f < 64; ++f) a = fmaf(ad[f], sW1[f * 32 + j], a);
    a = a > 0.0f ? a : 0.5f * a;  // LeakyReLU(0.5)
    logit = fmaf(a, sW2[j], logit);
  }
  red[tid] = logit;
  __syncthreads();
  if (tid == 0) {
    float mx = red[0];
    for (int i = 1; i < 128; ++i) mx = fmaxf(mx, red[i]);
    float sm = 0.0f;
    for (int i = 0; i < 128; ++i) sm += __expf(red[i] - mx);
    s_mx = mx; s_sum = sm;
  }
  __syncthreads();
  alpha[tid] = __expf(logit - s_mx) / s_sum;
}

// ---------------------------------------------------------------------------
// K1b: transpose w_a1[0:256][128] fp32 -> w1T[128 n][256 m] bf16.
// 4 blocks x 256 threads, each block 64 m-rows.
// ---------------------------------------------------------------------------
__global__ __launch_bounds__(256) void k_tw(
    const float* __restrict__ w_a1, __hip_bfloat16* __restrict__ w1T) {
  __shared__ float tile[64][132];
  int blk = blockIdx.x;
  int tid = threadIdx.x;
  #pragma unroll
  for (int i = 0; i < 32; ++i) {
    int idx = i * 256 + tid;
    int r = idx >> 7, c = idx & 127;
    tile[r][c] = w_a1[(size_t)(blk * 64 + r) * 128 + c];
  }
  __syncthreads();
  int n = tid >> 1, mh = tid & 1;
  unsigned* dst = reinterpret_cast<unsigned*>(&w1T[(size_t)n * 256 + blk * 64 + mh * 32]);
  #pragma unroll
  for (int i = 0; i < 16; ++i) {
    float a = tile[mh * 32 + 2 * i][n];
    float b = tile[mh * 32 + 2 * i + 1][n];
    dst[i] = pack2(a, b);
  }
}

// ---------------------------------------------------------------------------
// K2: EP[b,d,k] = exp(clamp(2*(alpha[d]*sum_tau X[b,tau,d]*w_a1[256+tau,k] + b_a1[k])))
// One block per b. 256 threads, outputs 128x128.
// ---------------------------------------------------------------------------
__global__ __launch_bounds__(256) void k_ep(
    const float* __restrict__ X, const float* __restrict__ w_a1,
    const float* __restrict__ b_a1, const float* __restrict__ alpha,
    float* __restrict__ EP) {
  __shared__ float Xb[64][128];
  __shared__ float Wx[64][128];
  int b = blockIdx.x;
  int tid = threadIdx.x;
  #pragma unroll
  for (int i = 0; i < 8; ++i) {
    int l4 = i * 256 + tid;
    int r = l4 >> 5, c4 = l4 & 31;
    st4(&Xb[r][c4 * 4], ld4(&X[((size_t)b * 64 + r) * 128 + c4 * 4]));
    st4(&Wx[r][c4 * 4], ld4(&w_a1[(size_t)(256 + r) * 128 + c4 * 4]));
  }
  __syncthreads();
  int dg = tid & 15, kg = tid >> 4;
  float acc[8][8] = {};
  #pragma unroll 4
  for (int tau = 0; tau < 64; ++tau) {
    float4 xa0 = ld4(&Xb[tau][dg * 4]);
    float4 xa1 = ld4(&Xb[tau][64 + dg * 4]);
    float4 wa0 = ld4(&Wx[tau][kg * 4]);
    float4 wa1 = ld4(&Wx[tau][64 + kg * 4]);
    #pragma unroll
    for (int i = 0; i < 8; ++i) {
      float xv = (i < 4) ? f4c(xa0, i) : f4c(xa1, i - 4);
      #pragma unroll
      for (int j = 0; j < 4; ++j) {
        acc[i][j]     = fmaf(xv, f4c(wa0, j), acc[i][j]);
        acc[i][j + 4] = fmaf(xv, f4c(wa1, j), acc[i][j + 4]);
      }
    }
  }
  float4 ba0 = ld4(&b_a1[kg * 4]);
  float4 ba1v = ld4(&b_a1[64 + kg * 4]);
  #pragma unroll
  for (int i = 0; i < 8; ++i) {
    int drow = (i < 4) ? dg * 4 + i : 64 + dg * 4 + (i - 4);
    float al = alpha[drow];
    float4 o0, o1;
    float* p0 = &o0.x; float* p1 = &o1.x;
    #pragma unroll
    for (int j = 0; j < 4; ++j) {
      float v0 = 2.0f * fmaf(al, acc[i][j],     f4c(ba0, j));
      float v1 = 2.0f * fmaf(al, acc[i][j + 4], f4c(ba1v, j));
      p0[j] = __expf(fminf(fmaxf(v0, -40.0f), 40.0f));
      p1[j] = __expf(fminf(fmaxf(v1, -40.0f), 40.0f));
    }
    st4(&EP[((size_t)b * 128 + drow) * 128 + kg * 4], o0);
    st4(&EP[((size_t)b * 128 + drow) * 128 + 64 + kg * 4], o1);
  }
}

// ---------------------------------------------------------------------------
// K3: fused gxw + LSTM recurrence via bf16 MFMA. v3:
//  - double-buffered kB -> ONE barrier per step
//  - X prefetched ~3 steps ahead (HBM latency off the serial path)
//  - x-part and h-part MFMA chains split (4-deep each) then summed
//  - S written as bf16 (only consumer is k_eq's bf16 MFMA)
// 32 blocks x 512 threads; block owns 16 batches.
// ---------------------------------------------------------------------------
__global__ __launch_bounds__(512, 1) void k_rec(
    const float* __restrict__ X, const float* __restrict__ w_ih,
    const float* __restrict__ w_hh, const float* __restrict__ b_ih,
    const float* __restrict__ b_hh, const float* __restrict__ alpha,
    __hip_bfloat16* __restrict__ S) {
  // kB[buf][b][k], k in [0,256): 0..127 = x_t(d), 128..255 = h(m). bf16.
  // 16-byte granule XOR swizzle: granule g of row b stored at g^(b&7).
  __shared__ unsigned short kB[2][16 * 256];
  int tid = threadIdx.x;
  int wv = tid >> 6, l = tid & 63, lg = l >> 4, lr = l & 15;
  int b0 = blockIdx.x * 16;

  // ---- A fragments: afr[ks][quad], ks 0..3 = w_ih*alpha, 4..7 = w_hh ----
  bf16x8 afr[8][4];
  #pragma unroll
  for (int ks = 0; ks < 8; ++ks) {
    int kb = (ks & 3) * 32 + lg * 8;
    float4 a0, a1;
    if (ks < 4) { a0 = ld4(&alpha[kb]); a1 = ld4(&alpha[kb + 4]); }
    #pragma unroll
    for (int q = 0; q < 4; ++q) {
      int j = q * 128 + wv * 16 + lr;
      const float* src = (ks < 4) ? &w_ih[(size_t)j * 128 + kb]
                                  : &w_hh[(size_t)j * 128 + kb];
      float4 f0 = ld4(src), f1 = ld4(src + 4);
      if (ks < 4) {
        f0.x *= a0.x; f0.y *= a0.y; f0.z *= a0.z; f0.w *= a0.w;
        f1.x *= a1.x; f1.y *= a1.y; f1.z *= a1.z; f1.w *= a1.w;
      }
      bf16x8 fr;
      fr[0] = (__bf16)f0.x; fr[1] = (__bf16)f0.y;
      fr[2] = (__bf16)f0.z; fr[3] = (__bf16)f0.w;
      fr[4] = (__bf16)f1.x; fr[5] = (__bf16)f1.y;
      fr[6] = (__bf16)f1.z; fr[7] = (__bf16)f1.w;
      afr[ks][q] = fr;
    }
  }

  // ---- biases per C-slot: j = q*128 + wv*16 + lg*4 + r ----
  float bias[4][4];
  #pragma unroll
  for (int q = 0; q < 4; ++q)
    #pragma unroll
    for (int r = 0; r < 4; ++r) {
      int j = q * 128 + wv * 16 + lg * 4 + r;
      bias[q][r] = b_ih[j] + b_hh[j];
    }

  alignas(16) float hA[4] = {0.f, 0.f, 0.f, 0.f};
  alignas(16) float cA[4] = {0.f, 0.f, 0.f, 0.f};

  int bi = tid >> 5, d0 = (tid & 31) * 4;              // x-staging role
  int m0 = wv * 16 + lg * 4;                           // this lane's h rows
  int k0 = 128 + m0;
  int xoff = bi * 256 + (((d0 >> 3) ^ (bi & 7)) << 3) + (d0 & 7);
  int hoff = lr * 256 + (((k0 >> 3) ^ (lr & 7)) << 3) + (k0 & 7);

  const float* xbase = &X[(size_t)(b0 + bi) * 64 * 128 + d0];

  // ---- prologue: x(0) + h(0)=0 into kB[0]; prefetch x(1), x(2) ----
  {
    float4 x0 = ld4(xbase);
    uint2 xu; xu.x = pack2(x0.x, x0.y); xu.y = pack2(x0.z, x0.w);
    *reinterpret_cast<uint2*>(&kB[0][xoff]) = xu;
    uint2 z; z.x = 0u; z.y = 0u;
    *reinterpret_cast<uint2*>(&kB[0][hoff]) = z;
  }
  float4 xa = ld4(xbase + 1 * 128);
  float4 xb = ld4(xbase + 2 * 128);
  __syncthreads();

  for (int t = 0; t < 64; ++t) {
    int cur = t & 1, nxt = cur ^ 1;

    // ---- B fragments from kB[cur] (first: on the critical path) ----
    bf16x8 bfr[8];
    #pragma unroll
    for (int ks = 0; ks < 8; ++ks) {
      int kb = ks * 32 + lg * 8;
      int idx = lr * 256 + (((kb >> 3) ^ (lr & 7)) << 3) + (kb & 7);
      bfr[ks] = *reinterpret_cast<const bf16x8*>(&kB[cur][idx]);
    }

    // ---- prefetch x(t+3) (consumed two iterations from now) ----
    int tn = (t + 3 < 64) ? t + 3 : 63;
    float4 xc = ld4(xbase + (size_t)tn * 128);

    // ---- S store: pre-update h,c (bf16) ----
    size_t srow = ((size_t)(t * 512) + b0 + lr) * 256;
    uint2 hS; hS.x = pack2(hA[0], hA[1]); hS.y = pack2(hA[2], hA[3]);
    uint2 cS; cS.x = pack2(cA[0], cA[1]); cS.y = pack2(cA[2], cA[3]);
    *reinterpret_cast<uint2*>(&S[srow + m0]) = hS;
    *reinterpret_cast<uint2*>(&S[srow + 128 + m0]) = cS;

    // ---- MFMA: x-part and h-part chains in parallel (4-deep each) ----
    f32x4 aX[4], aH[4];
    #pragma unroll
    for (int q = 0; q < 4; ++q) { aX[q] = (f32x4){0.f,0.f,0.f,0.f}; aH[q] = (f32x4){0.f,0.f,0.f,0.f}; }
    #pragma unroll
    for (int ks = 0; ks < 4; ++ks) {
      #pragma unroll
      for (int q = 0; q < 4; ++q)
        aX[q] = __builtin_amdgcn_mfma_f32_16x16x32_bf16(afr[ks][q], bfr[ks], aX[q], 0, 0, 0);
      #pragma unroll
      for (int q = 0; q < 4; ++q)
        aH[q] = __builtin_amdgcn_mfma_f32_16x16x32_bf16(afr[ks + 4][q], bfr[ks + 4], aH[q], 0, 0, 0);
    }

    // ---- cell update ----
    #pragma unroll
    for (int r = 0; r < 4; ++r) {
      float g0 = aX[0][r] + aH[0][r] + bias[0][r];
      float g1 = aX[1][r] + aH[1][r] + bias[1][r];
      float g2 = aX[2][r] + aH[2][r] + bias[2][r];
      float g3 = aX[3][r] + aH[3][r] + bias[3][r];
      float ig = sigmoid_fast(g0);
      float fg = sigmoid_fast(g1);
      float gg = tanh_fast(g2);
      float og = sigmoid_fast(g3);
      float cn = fmaf(fg, cA[r], ig * gg);
      float hn = og * tanh_fast(cn);
      cA[r] = cn;
      hA[r] = hn;
    }

    // ---- write x(t+1), h(t+1) into kB[nxt] ----
    uint2 xu; xu.x = pack2(xa.x, xa.y); xu.y = pack2(xa.z, xa.w);
    *reinterpret_cast<uint2*>(&kB[nxt][xoff]) = xu;
    uint2 hu; hu.x = pack2(hA[0], hA[1]); hu.y = pack2(hA[2], hA[3]);
    *reinterpret_cast<uint2*>(&kB[nxt][hoff]) = hu;
    xa = xb; xb = xc;
    __syncthreads();
  }
}

// ---------------------------------------------------------------------------
// K4: EQ[t*512+b, n] = exp(clamp(2 * sum_{m<256} S[t*512+b, m]*w1T[n, m]))
// bf16 MFMA, register-only (no LDS): 256 blocks x 256 thr (4 waves),
// block = 128 rows x 128 n; wave = 32 rows. 128 MFMA/wave.
// ---------------------------------------------------------------------------
__global__ __launch_bounds__(256, 1) void k_eq(
    const __hip_bfloat16* __restrict__ S, const __hip_bfloat16* __restrict__ w1T,
    float* __restrict__ EQ) {
  int tid = threadIdx.x;
  int wv = tid >> 6, l = tid & 63;
  int lr = l & 15, lg = l >> 4;
  int r0 = blockIdx.x * 128 + wv * 32;

  bf16x8 a[2][8];
  #pragma unroll
  for (int ri = 0; ri < 2; ++ri)
    #pragma unroll
    for (int ks = 0; ks < 8; ++ks)
      a[ri][ks] = *reinterpret_cast<const bf16x8*>(
          &S[(size_t)(r0 + ri * 16 + lr) * 256 + ks * 32 + lg * 8]);

  f32x4 acc[2][8];
  #pragma unroll
  for (int ri = 0; ri < 2; ++ri)
    #pragma unroll
    for (int nj = 0; nj < 8; ++nj) acc[ri][nj] = (f32x4){0.f, 0.f, 0.f, 0.f};

  #pragma unroll
  for (int nj = 0; nj < 8; ++nj) {
    bf16x8 bf[8];
    #pragma unroll
    for (int ks = 0; ks < 8; ++ks)
      bf[ks] = *reinterpret_cast<const bf16x8*>(
          &w1T[(size_t)(nj * 16 + lr) * 256 + ks * 32 + lg * 8]);
    #pragma unroll
    for (int ks = 0; ks < 8; ++ks) {
      acc[0][nj] = __builtin_amdgcn_mfma_f32_16x16x32_bf16(a[0][ks], bf[ks], acc[0][nj], 0, 0, 0);
      acc[1][nj] = __builtin_amdgcn_mfma_f32_16x16x32_bf16(a[1][ks], bf[ks], acc[1][nj], 0, 0, 0);
    }
  }

  #pragma unroll
  for (int ri = 0; ri < 2; ++ri)
    #pragma unroll
    for (int nj = 0; nj < 8; ++nj)
      #pragma unroll
      for (int r = 0; r < 4; ++r) {
        int grow = r0 + ri * 16 + lg * 4 + r;
        int n = nj * 16 + lr;
        float v = 2.0f * acc[ri][nj][r];
        EQ[(size_t)grow * 128 + n] = __expf(fminf(fmaxf(v, -40.f), 40.f));
      }
}

// ---------------------------------------------------------------------------
// K5: per (b): e'[t,d] = -2*sum_k w_a2[k]*rcp(EP[b,d,k]*EQ[t,b,k]+1);
// softmax over d; out[b,t,d] = sm * alpha[d] * X[b,t,d].
// v3: 8 t's per round -> 16 barriers/block (was 128); softmax phase uses
// all 8 waves (wave wv reduces t=rnd*8+wv).
// ---------------------------------------------------------------------------
__global__ __launch_bounds__(512, 2) void k_attn(
    const float* __restrict__ EP, const float* __restrict__ EQ,
    const float* __restrict__ w_a2, const float* __restrict__ alpha,
    const float* __restrict__ X, float* __restrict__ out) {
  __shared__ float EQs[64][128];
  __shared__ float e_lds[8][128];
  int b = blockIdx.x;
  int tid = threadIdx.x;
  #pragma unroll
  for (int i = 0; i < 4; ++i) {
    int l4 = i * 512 + tid;
    int t = l4 >> 5, k4 = l4 & 31;
    st4(&EQs[t][k4 * 4], ld4(&EQ[((size_t)t * 512 + b) * 128 + k4 * 4]));
  }
  int d = tid >> 2, s = tid & 3;
  float4 ep[8], w2r[8];
  #pragma unroll
  for (int q = 0; q < 8; ++q) {
    ep[q]  = ld4(&EP[((size_t)b * 128 + d) * 128 + s * 32 + q * 4]);
    w2r[q] = ld4(&w_a2[s * 32 + q * 4]);
  }
  int wv = tid >> 6, l = tid & 63;
  float al0 = alpha[l], al1 = alpha[64 + l];
  __syncthreads();

  for (int rnd = 0; rnd < 8; ++rnd) {
    #pragma unroll
    for (int it = 0; it < 8; ++it) {
      int t = rnd * 8 + it;
      float p = 0.0f;
      #pragma unroll
      for (int q = 0; q < 8; ++q) {
        float4 eq = ld4(&EQs[t][s * 32 + q * 4]);
        p = fmaf(w2r[q].x, fast_rcp(fmaf(ep[q].x, eq.x, 1.0f)), p);
        p = fmaf(w2r[q].y, fast_rcp(fmaf(ep[q].y, eq.y, 1.0f)), p);
        p = fmaf(w2r[q].z, fast_rcp(fmaf(ep[q].z, eq.z, 1.0f)), p);
        p = fmaf(w2r[q].w, fast_rcp(fmaf(ep[q].w, eq.w, 1.0f)), p);
      }
      p += __shfl_xor(p, 1);
      p += __shfl_xor(p, 2);
      if (s == 0) e_lds[it][d] = -2.0f * p;
    }
    __syncthreads();
    {
      int t = rnd * 8 + wv;
      float v0 = e_lds[wv][l], v1 = e_lds[wv][64 + l];
      float mx = fmaxf(v0, v1);
      #pragma unroll
      for (int o = 1; o < 64; o <<= 1) mx = fmaxf(mx, __shfl_xor(mx, o));
      float e0 = __expf(v0 - mx), e1 = __expf(v1 - mx);
      float sm = e0 + e1;
      #pragma unroll
      for (int o = 1; o < 64; o <<= 1) sm += __shfl_xor(sm, o);
      float inv = fast_rcp(sm);
      size_t ro = ((size_t)b * 64 + t) * 128;
      out[ro + l]      = e0 * inv * al0 * X[ro + l];
      out[ro + 64 + l] = e1 * inv * al1 * X[ro + 64 + l];
    }
    __syncthreads();
  }
}

// ---------------------------------------------------------------------------
extern "C" void kernel_launch(void* const* d_in, const int* in_sizes, int n_in,
                              void* d_out, int out_size, void* d_ws, size_t ws_size,
                              hipStream_t stream) {
  const float* X    = (const float*)d_in[0];
  const float* AD   = (const float*)d_in[1];
  const float* W1   = (const float*)d_in[2];
  const float* B1   = (const float*)d_in[3];
  const float* W2   = (const float*)d_in[4];
  const float* B2   = (const float*)d_in[5];
  const float* w_a1 = (const float*)d_in[6];
  const float* b_a1 = (const float*)d_in[7];
  const float* w_a2 = (const float*)d_in[8];
  // d_in[9] = b_a2: softmax-invariant, unused
  const float* w_ih = (const float*)d_in[10];
  const float* w_hh = (const float*)d_in[11];
  const float* b_ih = (const float*)d_in[12];
  const float* b_hh = (const float*)d_in[13];
  float* out = (float*)d_out;
  float* ws = (float*)d_ws;

  // workspace layout (float units)
  float* alpha = ws;                                   // 256
  float* EQ    = ws + 256;                             // 32768*128   = 4194304
  float* EP    = EQ + 4194304;                         // 65536*128   = 8388608
  __hip_bfloat16* S   = (__hip_bfloat16*)(EP + 8388608);        // 32768*256 bf16
  __hip_bfloat16* w1T = (__hip_bfloat16*)(EP + 8388608 + 4194304); // 128*256 bf16
  // total ~= 16.8M floats ~= 67 MB

  hipLaunchKernelGGL(k_alpha, dim3(1),   dim3(128), 0, stream, AD, W1, B1, W2, B2, alpha);
  hipLaunchKernelGGL(k_tw,    dim3(4),   dim3(256), 0, stream, w_a1, w1T);
  hipLaunchKernelGGL(k_ep,    dim3(512), dim3(256), 0, stream, X, w_a1, b_a1, alpha, EP);
  hipLaunchKernelGGL(k_rec,   dim3(32),  dim3(512), 0, stream, X, w_ih, w_hh, b_ih, b_hh, alpha, S);
  hipLaunchKernelGGL(k_eq,    dim3(256), dim3(256), 0, stream, S, w1T, EQ);
  hipLaunchKernelGGL(k_attn,  dim3(512), dim3(512), 0, stream, EP, EQ, w_a2, alpha, X, out);
}